// Round 7
// baseline (270.649 us; speedup 1.0000x reference)
//
#include <hip/hip_runtime.h>

#define TINYF 1e-8f
#define NITER 50
#define HSTR  52   // halo row stride: 2-col zero pad each side of 48

__device__ __forceinline__ float bperm(int addr4, float v) {
    return __int_as_float(__builtin_amdgcn_ds_bpermute(addr4, __float_as_int(v)));
}

// 21-tap 5x5 conv (corners dropped), straight-line, no arrays-of-pointers.
// Lane owns strip rows 3lr..3lr+2 as x[i][0..6] = cols 3lc-2..3lc+4
// (edge cols pre-zeroed at crop boundary). Window rows j=0,1 from lane-16
// (or halo buffer hT for lr==0); j=5,6 from lane+16 (or hB for lr==3).
#define LOAD_UP(ROW) \
    f0=bperm(upA,x[ROW][0]); f1=bperm(upA,x[ROW][1]); f2=bperm(upA,x[ROW][2]); \
    f3=bperm(upA,x[ROW][3]); f4=bperm(upA,x[ROW][4]); f5=bperm(upA,x[ROW][5]); \
    f6=bperm(upA,x[ROW][6]);
#define LOAD_DN(ROW) \
    f0=bperm(dnA,x[ROW][0]); f1=bperm(dnA,x[ROW][1]); f2=bperm(dnA,x[ROW][2]); \
    f3=bperm(dnA,x[ROW][3]); f4=bperm(dnA,x[ROW][4]); f5=bperm(dnA,x[ROW][5]); \
    f6=bperm(dnA,x[ROW][6]);
#define OWN(ROW) \
    f0=x[ROW][0]; f1=x[ROW][1]; f2=x[ROW][2]; f3=x[ROW][3]; f4=x[ROW][4]; \
    f5=x[ROW][5]; f6=x[ROW][6];
#define OVR_TOP(OFF) \
    if (lr == 0) { f0=f1=f2=f3=f4=f5=f6=0.f; \
        if (hasTop) { f0=hT[(OFF)+0]; f1=hT[(OFF)+1]; f2=hT[(OFF)+2]; \
                      f3=hT[(OFF)+3]; f4=hT[(OFF)+4]; f5=hT[(OFF)+5]; \
                      f6=hT[(OFF)+6]; } }
#define OVR_BOT(OFF) \
    if (lr == 3) { f0=f1=f2=f3=f4=f5=f6=0.f; \
        if (hasBot) { f0=hB[(OFF)+0]; f1=hB[(OFF)+1]; f2=hB[(OFF)+2]; \
                      f3=hB[(OFF)+3]; f4=hB[(OFF)+4]; f5=hB[(OFF)+5]; \
                      f6=hB[(OFF)+6]; } }
#define MKS1  s10=f1+f3; s11=f2+f4; s12=f3+f5;
#define MKS2  s20=f0+f4; s21=f1+f5; s22=f2+f6;
#define ACC_D0(A) A##0+=k00*f2+k01*s10+k02*s20; A##1+=k00*f3+k01*s11+k02*s21; A##2+=k00*f4+k01*s12+k02*s22;
#define ACC_D1(A) A##0+=k10*f2+k11*s10+k12*s20; A##1+=k10*f3+k11*s11+k12*s21; A##2+=k10*f4+k11*s12+k12*s22;
#define ACC_D2(A) A##0+=k20*f2+k21*s10; A##1+=k20*f3+k21*s11; A##2+=k20*f4+k21*s12;

__device__ __forceinline__ void conv21(
    const float (&x)[3][7],
    const float* hT, const float* hB, bool hasTop, bool hasBot,
    int lr, int upA, int dnA,
    float k00, float k01, float k02,
    float k10, float k11, float k12,
    float k20, float k21,
    float (&acc)[3][3])
{
    float f0, f1, f2, f3, f4, f5, f6;
    float s10, s11, s12, s20, s21, s22;
    float a00 = 0.f, a01 = 0.f, a02 = 0.f;
    float a10 = 0.f, a11 = 0.f, a12 = 0.f;
    float a20 = 0.f, a21 = 0.f, a22 = 0.f;

    LOAD_UP(1) OVR_TOP(0)            // j=0: row R0-2
    MKS1
    ACC_D2(a0)
    LOAD_UP(2) OVR_TOP(HSTR)         // j=1: row R0-1
    MKS1 MKS2
    ACC_D1(a0) ACC_D2(a1)
    OWN(0)                           // j=2: row R0
    MKS1 MKS2
    ACC_D0(a0) ACC_D1(a1) ACC_D2(a2)
    OWN(1)                           // j=3: row R0+1
    MKS1 MKS2
    ACC_D1(a0) ACC_D0(a1) ACC_D1(a2)
    OWN(2)                           // j=4: row R0+2
    MKS1 MKS2
    ACC_D2(a0) ACC_D1(a1) ACC_D0(a2)
    LOAD_DN(0) OVR_BOT(0)            // j=5: row R0+3
    MKS1 MKS2
    ACC_D2(a1) ACC_D1(a2)
    LOAD_DN(1) OVR_BOT(HSTR)         // j=6: row R0+4
    MKS1
    ACC_D2(a2)

    acc[0][0]=a00; acc[0][1]=a01; acc[0][2]=a02;
    acc[1][0]=a10; acc[1][1]=a11; acc[1][2]=a12;
    acc[2][0]=a20; acc[2][1]=a21; acc[2][2]=a22;
}

__global__ __launch_bounds__(256, 3)
void sinkhorn_lean(const float* __restrict__ hm_gt,
                   const float* __restrict__ hm_pred,
                   const int* __restrict__ tops,
                   float* __restrict__ out) {
    __shared__ __align__(16) float Hu[4 * 4 * HSTR];
    __shared__ __align__(16) float Hv[4 * 4 * HSTR];
    __shared__ float sred[8];

    const int t = threadIdx.x;
    const int w = t >> 6;                 // wave 0..3 -> strip rows 12w..12w+11
    const int l = t & 63;
    const int lr = l >> 4, lc = l & 15;   // 4x16 lane grid, 3x3 px tile

    const int blk = blockIdx.x;
    const int bi = blk / 40, rr = (blk / 5) % 8, cc = blk % 5;
    const int y0 = tops[(bi * 8 + rr) * 2 + 0];
    const int x0 = tops[(bi * 8 + rr) * 2 + 1];
    const float* srcA = hm_gt + (size_t)(bi * 5 + cc) * 25600;
    const float* srcB = hm_pred + (size_t)(bi * 5 + cc) * 25600;

    const int upA = ((l - 16) & 63) << 2;
    const int dnA = ((l + 16) & 63) << 2;
    const int lA  = ((l - 1) & 63) << 2;
    const int rA  = ((l + 1) & 63) << 2;

    const bool hasTop = (w > 0), hasBot = (w < 3);
    const int wUp = hasTop ? w - 1 : 0, wDn = hasBot ? w + 1 : 3;
    // read pointers (lane-local, hoisted): two consecutive rows at +0/+HSTR
    const float* hTu = Hu + (wUp * 4 + 2) * HSTR + 3 * lc;
    const float* hBu = Hu + (wDn * 4 + 0) * HSTR + 3 * lc;
    const float* hTv = Hv + (wUp * 4 + 2) * HSTR + 3 * lc;
    const float* hBv = Hv + (wDn * 4 + 0) * HSTR + 3 * lc;
    // write pointers (edge lanes only)
    float* wTopU = Hu + (w * 4 + 0) * HSTR + 2 + 3 * lc;
    float* wBotU = Hu + (w * 4 + 2) * HSTR + 2 + 3 * lc;
    float* wTopV = Hv + (w * 4 + 0) * HSTR + 2 + 3 * lc;
    float* wBotV = Hv + (w * 4 + 2) * HSTR + 2 + 3 * lc;

    // zero halo buffers (pads stay zero forever)
    for (int p = t; p < 4 * 4 * HSTR; p += 256) { Hu[p] = 0.f; Hv[p] = 0.f; }

    // ---- load 3x3 tiles; block-reduce sums ----
    const int gr = y0 + 12 * w + 3 * lr;
    const int gc = x0 + 3 * lc;
    float va[3][3], vb[3][3];
    float sA = 0.f, sB = 0.f;
#pragma unroll
    for (int i = 0; i < 3; ++i)
#pragma unroll
        for (int c = 0; c < 3; ++c) {
            const float A = srcA[(gr + i) * 160 + gc + c];
            const float B = srcB[(gr + i) * 160 + gc + c];
            va[i][c] = A; vb[i][c] = B;
            sA += A; sB += B;
        }
#pragma unroll
    for (int o = 1; o < 64; o <<= 1) {
        sA += __shfl_xor(sA, o, 64);
        sB += __shfl_xor(sB, o, 64);
    }
    if (l == 0) { sred[w] = sA; sred[4 + w] = sB; }
    __syncthreads();
    sA = sred[0] + sred[1] + sred[2] + sred[3];
    sB = sred[4] + sred[5] + sred[6] + sred[7];
    const float nA = 1.0f / (sA + TINYF);
    const float nB = 1.0f / (sB + TINYF);
#pragma unroll
    for (int i = 0; i < 3; ++i)
#pragma unroll
        for (int c = 0; c < 3; ++c) { va[i][c] *= nA; vb[i][c] *= nB; }

    // ---- u0 = 1/n (extended, crop-edge cols zeroed) ----
    float xu[3][7], xv[3][7];
    const float u0 = 1.0f / 2304.0f;
#pragma unroll
    for (int i = 0; i < 3; ++i) {
#pragma unroll
        for (int k = 0; k < 7; ++k) xu[i][k] = u0;
        if (lc == 0)  { xu[i][0] = 0.f; xu[i][1] = 0.f; }
        if (lc == 15) { xu[i][5] = 0.f; xu[i][6] = 0.f; }
    }
    if (lr == 0) {
#pragma unroll
        for (int c = 0; c < 3; ++c) { wTopU[c] = xu[0][c+2]; wTopU[HSTR+c] = xu[1][c+2]; }
    }
    if (lr == 3) {
#pragma unroll
        for (int c = 0; c < 3; ++c) { wBotU[c] = xu[1][c+2]; wBotU[HSTR+c] = xu[2][c+2]; }
    }
    __syncthreads();

    // Gibbs weights
    const float e10 = expf(-1.0f / 0.1f);
    const float e2  = expf(-sqrtf(2.0f) / 0.1f);
    const float e20 = expf(-2.0f / 0.1f);
    const float e5  = expf(-sqrtf(5.0f) / 0.1f);

    float acc[3][3];

    // ---- Sinkhorn iterations ----
#pragma unroll 1
    for (int it = 0; it < NITER; ++it) {
        // ---- u @ K -> v ----
        conv21(xu, hTu, hBu, hasTop, hasBot, lr, upA, dnA,
               1.0f, e10, e20, e10, e2, e5, e20, e5, acc);
#pragma unroll
        for (int i = 0; i < 3; ++i)
#pragma unroll
            for (int c = 0; c < 3; ++c)
                xv[i][c + 2] = vb[i][c] * __builtin_amdgcn_rcpf(acc[i][c] + TINYF);
#pragma unroll
        for (int i = 0; i < 3; ++i) {
            const float h0 = bperm(lA, xv[i][3]);
            const float h1 = bperm(lA, xv[i][4]);
            const float h2 = bperm(rA, xv[i][2]);
            const float h3 = bperm(rA, xv[i][3]);
            xv[i][0] = (lc == 0)  ? 0.f : h0;
            xv[i][1] = (lc == 0)  ? 0.f : h1;
            xv[i][5] = (lc == 15) ? 0.f : h2;
            xv[i][6] = (lc == 15) ? 0.f : h3;
        }
        if (lr == 0) {
#pragma unroll
            for (int c = 0; c < 3; ++c) { wTopV[c] = xv[0][c+2]; wTopV[HSTR+c] = xv[1][c+2]; }
        }
        if (lr == 3) {
#pragma unroll
            for (int c = 0; c < 3; ++c) { wBotV[c] = xv[1][c+2]; wBotV[HSTR+c] = xv[2][c+2]; }
        }
        __syncthreads();

        // ---- v @ K -> u ----
        conv21(xv, hTv, hBv, hasTop, hasBot, lr, upA, dnA,
               1.0f, e10, e20, e10, e2, e5, e20, e5, acc);
#pragma unroll
        for (int i = 0; i < 3; ++i)
#pragma unroll
            for (int c = 0; c < 3; ++c)
                xu[i][c + 2] = va[i][c] * __builtin_amdgcn_rcpf(acc[i][c] + TINYF);
#pragma unroll
        for (int i = 0; i < 3; ++i) {
            const float h0 = bperm(lA, xu[i][3]);
            const float h1 = bperm(lA, xu[i][4]);
            const float h2 = bperm(rA, xu[i][2]);
            const float h3 = bperm(rA, xu[i][3]);
            xu[i][0] = (lc == 0)  ? 0.f : h0;
            xu[i][1] = (lc == 0)  ? 0.f : h1;
            xu[i][5] = (lc == 15) ? 0.f : h2;
            xu[i][6] = (lc == 15) ? 0.f : h3;
        }
        if (lr == 0) {
#pragma unroll
            for (int c = 0; c < 3; ++c) { wTopU[c] = xu[0][c+2]; wTopU[HSTR+c] = xu[1][c+2]; }
        }
        if (lr == 3) {
#pragma unroll
            for (int c = 0; c < 3; ++c) { wBotU[c] = xu[1][c+2]; wBotU[HSTR+c] = xu[2][c+2]; }
        }
        __syncthreads();
    }

    // ---- loss: (u @ M) . v, M = K .* dist (center 0, corners dropped) ----
    const float s2f = sqrtf(2.0f), s5f = sqrtf(5.0f);
    conv21(xu, hTu, hBu, hasTop, hasBot, lr, upA, dnA,
           0.0f, e10, e20 * 2.0f, e10, e2 * s2f, e5 * s5f, e20 * 2.0f, e5 * s5f,
           acc);
    float lsum = 0.f;
#pragma unroll
    for (int i = 0; i < 3; ++i)
#pragma unroll
        for (int c = 0; c < 3; ++c)
            lsum += acc[i][c] * xv[i][c + 2];

#pragma unroll
    for (int o = 1; o < 64; o <<= 1) lsum += __shfl_xor(lsum, o, 64);
    if (l == 0) atomicAdd(out, lsum);
}

extern "C" void kernel_launch(void* const* d_in, const int* in_sizes, int n_in,
                              void* d_out, int out_size, void* d_ws, size_t ws_size,
                              hipStream_t stream) {
    (void)in_sizes; (void)n_in; (void)out_size; (void)d_ws; (void)ws_size;
    const float* hm_gt = (const float*)d_in[0];
    const float* hm_pred = (const float*)d_in[1];
    const int* tops = (const int*)d_in[2];
    float* out = (float*)d_out;

    hipMemsetAsync(out, 0, sizeof(float), stream);
    sinkhorn_lean<<<dim3(640), dim3(256), 0, stream>>>(hm_gt, hm_pred, tops, out);
}

// Round 8
// 229.818 us; speedup vs baseline: 1.1777x; 1.1777x over previous
//
#include <hip/hip_runtime.h>

#define TINYF 1e-8f
#define NITER 50
// LDS halo store: per field, 7 blocks of [4 rows][16 lanes][4 floats].
// Block b holds boundary rows written by wave b-1 (rows 0,1 = its strip rows
// 0,1 from lr==0 lanes; rows 2,3 = strip rows 10,11 from lr==3 lanes).
// Blocks 0 and 5 are never written (stay zero -> crop edge zeros); block 6 = trash.
#define HBLK 256
#define HFLD (7 * HBLK)

__device__ __forceinline__ float bperm(int addr4, float v) {
    return __int_as_float(__builtin_amdgcn_ds_bpermute(addr4, __float_as_int(v)));
}
// lane i <- lane i-1 within 16-lane DPP row; 0 at row edge (= crop left edge)
__device__ __forceinline__ float dpp_shr1(float v) {
    return __int_as_float(__builtin_amdgcn_update_dpp(0, __float_as_int(v), 0x111, 0xf, 0xf, true));
}
// lane i <- lane i+1 within 16-lane DPP row; 0 at row edge (= crop right edge)
__device__ __forceinline__ float dpp_shl1(float v) {
    return __int_as_float(__builtin_amdgcn_update_dpp(0, __float_as_int(v), 0x101, 0xf, 0xf, true));
}

// window-row prep: lane owns cols 3lc..3lc+2 of this row as C0_,C1_,C2_
#define ROWF(C0_, C1_, C2_) \
    L2 = dpp_shr1(C1_); L1 = dpp_shr1(C2_); R1 = dpp_shl1(C0_); R2 = dpp_shl1(C1_); \
    s1a = L1 + C1_; s1b = C0_ + C2_; s1c = C1_ + R1; \
    s2a = L2 + C2_; s2b = L1 + R1; s2c = C0_ + R2;
#define ROWL(C0_, C1_, C2_) \
    L1 = dpp_shr1(C2_); R1 = dpp_shl1(C0_); \
    s1a = L1 + C1_; s1b = C0_ + C2_; s1c = C1_ + R1;
#define ADX(A0_, A1_, A2_, C0_, C1_, C2_, KA, KB, KC) \
    A0_ += KA * C0_ + KB * s1a + KC * s2a; \
    A1_ += KA * C1_ + KB * s1b + KC * s2b; \
    A2_ += KA * C2_ + KB * s1c + KC * s2c;
#define AD2X(A0_, A1_, A2_, C0_, C1_, C2_, KA, KB) \
    A0_ += KA * C0_ + KB * s1a; \
    A1_ += KA * C1_ + KB * s1b; \
    A2_ += KA * C2_ + KB * s1c;

// 21-tap 5x5 conv (corners dropped); F0..F8 = own 3x3 (row-major), halos in
// hA*(row-2) hB*(row-1) hC*(row+3) hD*(row+4). Same tap/order as R7 -> bit-identical.
#define CONV21(F0,F1,F2,F3,F4,F5,F6,F7,F8, K00,K01,K02,K10,K11,K12,K20,K21) \
  { float L1, L2, R1, R2, s1a, s1b, s1c, s2a, s2b, s2c; \
    acc0=acc1=acc2=acc3=acc4=acc5=acc6=acc7=acc8=0.f; \
    ROWL(hA0, hA1, hA2) \
    AD2X(acc0,acc1,acc2, hA0,hA1,hA2, K20,K21) \
    ROWF(hB0, hB1, hB2) \
    ADX (acc0,acc1,acc2, hB0,hB1,hB2, K10,K11,K12) \
    AD2X(acc3,acc4,acc5, hB0,hB1,hB2, K20,K21) \
    ROWF(F0, F1, F2) \
    ADX (acc0,acc1,acc2, F0,F1,F2, K00,K01,K02) \
    ADX (acc3,acc4,acc5, F0,F1,F2, K10,K11,K12) \
    AD2X(acc6,acc7,acc8, F0,F1,F2, K20,K21) \
    ROWF(F3, F4, F5) \
    ADX (acc0,acc1,acc2, F3,F4,F5, K10,K11,K12) \
    ADX (acc3,acc4,acc5, F3,F4,F5, K00,K01,K02) \
    ADX (acc6,acc7,acc8, F3,F4,F5, K10,K11,K12) \
    ROWF(F6, F7, F8) \
    AD2X(acc0,acc1,acc2, F6,F7,F8, K20,K21) \
    ADX (acc3,acc4,acc5, F6,F7,F8, K10,K11,K12) \
    ADX (acc6,acc7,acc8, F6,F7,F8, K00,K01,K02) \
    ROWF(hC0, hC1, hC2) \
    AD2X(acc3,acc4,acc5, hC0,hC1,hC2, K20,K21) \
    ADX (acc6,acc7,acc8, hC0,hC1,hC2, K10,K11,K12) \
    ROWL(hD0, hD1, hD2) \
    AD2X(acc6,acc7,acc8, hD0,hD1,hD2, K20,K21) \
  }

// update field G from acc, publish boundary rows, refresh G's halos
#define UPDATE_PREP(G, M, WP, RP) \
  { \
    G[0] = M[0] * __builtin_amdgcn_rcpf(acc0 + TINYF); \
    G[1] = M[1] * __builtin_amdgcn_rcpf(acc1 + TINYF); \
    G[2] = M[2] * __builtin_amdgcn_rcpf(acc2 + TINYF); \
    G[3] = M[3] * __builtin_amdgcn_rcpf(acc3 + TINYF); \
    G[4] = M[4] * __builtin_amdgcn_rcpf(acc4 + TINYF); \
    G[5] = M[5] * __builtin_amdgcn_rcpf(acc5 + TINYF); \
    G[6] = M[6] * __builtin_amdgcn_rcpf(acc6 + TINYF); \
    G[7] = M[7] * __builtin_amdgcn_rcpf(acc7 + TINYF); \
    G[8] = M[8] * __builtin_amdgcn_rcpf(acc8 + TINYF); \
    { float w0a = top ? G[0] : G[3], w0b = top ? G[1] : G[4], w0c = top ? G[2] : G[5]; \
      float w1a = top ? G[3] : G[6], w1b = top ? G[4] : G[7], w1c = top ? G[5] : G[8]; \
      *(float4*)(WP)      = make_float4(w0a, w0b, w0c, 0.f); \
      *(float4*)(WP + 64) = make_float4(w1a, w1b, w1c, 0.f); } \
    __syncthreads(); \
    hA0 = bperm(upA, G[3]); hA1 = bperm(upA, G[4]); hA2 = bperm(upA, G[5]); \
    hB0 = bperm(upA, G[6]); hB1 = bperm(upA, G[7]); hB2 = bperm(upA, G[8]); \
    hC0 = bperm(dnA, G[0]); hC1 = bperm(dnA, G[1]); hC2 = bperm(dnA, G[2]); \
    hD0 = bperm(dnA, G[3]); hD1 = bperm(dnA, G[4]); hD2 = bperm(dnA, G[5]); \
    { float4 q0 = *(const float4*)(RP); \
      float4 q1 = *(const float4*)(RP + 64); \
      hA0 = top ? q0.x : hA0; hA1 = top ? q0.y : hA1; hA2 = top ? q0.z : hA2; \
      hB0 = top ? q1.x : hB0; hB1 = top ? q1.y : hB1; hB2 = top ? q1.z : hB2; \
      hC0 = bot ? q0.x : hC0; hC1 = bot ? q0.y : hC1; hC2 = bot ? q0.z : hC2; \
      hD0 = bot ? q1.x : hD0; hD1 = bot ? q1.y : hD1; hD2 = bot ? q1.z : hD2; } \
  }

__global__ __launch_bounds__(256, 3)
void sinkhorn_dpp(const float* __restrict__ hm_gt,
                  const float* __restrict__ hm_pred,
                  const int* __restrict__ tops,
                  float* __restrict__ out) {
    __shared__ __align__(16) float H[2 * HFLD];
    __shared__ float sred[8];

    const int t = threadIdx.x;
    const int w = t >> 6;                 // wave: strip rows 12w..12w+11
    const int l = t & 63;
    const int lr = l >> 4, lc = l & 15;   // 4 strip bands x 16 col-tiles (3 cols each)
    const bool top = (lr == 0), bot = (lr == 3);

    const int blk = blockIdx.x;
    const int bi = blk / 40, rr = (blk / 5) % 8, cc = blk % 5;
    const int y0 = tops[(bi * 8 + rr) * 2 + 0];
    const int x0 = tops[(bi * 8 + rr) * 2 + 1];
    const float* srcA = hm_gt + (size_t)(bi * 5 + cc) * 25600;
    const float* srcB = hm_pred + (size_t)(bi * 5 + cc) * 25600;

    const int upA = ((l - 16) & 63) << 2;
    const int dnA = ((l + 16) & 63) << 2;

    float* Hu = H;
    float* Hv = H + HFLD;
    const int wblk = (top || bot) ? (w + 1) : 6;      // mid lanes -> trash block
    const int rblk = top ? w : (w + 2);               // w==0 top / w==3 bot hit zero blocks
    const int woff = wblk * HBLK + (top ? 0 : 2) * 64 + lc * 4;
    const int roff = rblk * HBLK + (top ? 2 : 0) * 64 + lc * 4;
    float* WPu = Hu + woff; const float* RPu = Hu + roff;
    float* WPv = Hv + woff; const float* RPv = Hv + roff;

    // ---- zero halo store (zero/trash blocks included) ----
    const float4 z4 = make_float4(0.f, 0.f, 0.f, 0.f);
    for (int p = t; p < 2 * HFLD / 4; p += 256) ((float4*)H)[p] = z4;

    // ---- load 3x3 tiles; block-reduce sums ----
    const int gr = y0 + 12 * w + 3 * lr;
    const int gc = x0 + 3 * lc;
    float va[9], vb[9];
    float sA = 0.f, sB = 0.f;
#pragma unroll
    for (int i = 0; i < 3; ++i)
#pragma unroll
        for (int c = 0; c < 3; ++c) {
            const float A = srcA[(gr + i) * 160 + gc + c];
            const float B = srcB[(gr + i) * 160 + gc + c];
            va[3 * i + c] = A; vb[3 * i + c] = B;
            sA += A; sB += B;
        }
#pragma unroll
    for (int o = 1; o < 64; o <<= 1) {
        sA += __shfl_xor(sA, o, 64);
        sB += __shfl_xor(sB, o, 64);
    }
    if (l == 0) { sred[w] = sA; sred[4 + w] = sB; }
    __syncthreads();   // also covers H zeroing
    sA = sred[0] + sred[1] + sred[2] + sred[3];
    sB = sred[4] + sred[5] + sred[6] + sred[7];
    const float nA = 1.0f / (sA + TINYF);
    const float nB = 1.0f / (sB + TINYF);
#pragma unroll
    for (int k = 0; k < 9; ++k) { va[k] *= nA; vb[k] *= nB; }

    // ---- u0 = 1/n; publish boundary; prep halos ----
    float xu[9], xv[9];
    const float u0 = 1.0f / 2304.0f;
#pragma unroll
    for (int k = 0; k < 9; ++k) xu[k] = u0;
    *(float4*)(WPu)      = make_float4(u0, u0, u0, 0.f);
    *(float4*)(WPu + 64) = make_float4(u0, u0, u0, 0.f);
    __syncthreads();
    float hA0, hA1, hA2, hB0, hB1, hB2, hC0, hC1, hC2, hD0, hD1, hD2;
    hA0 = hA1 = hA2 = hB0 = hB1 = hB2 = u0;
    hC0 = hC1 = hC2 = hD0 = hD1 = hD2 = u0;
    {
        float4 q0 = *(const float4*)(RPu);
        float4 q1 = *(const float4*)(RPu + 64);
        hA0 = top ? q0.x : hA0; hA1 = top ? q0.y : hA1; hA2 = top ? q0.z : hA2;
        hB0 = top ? q1.x : hB0; hB1 = top ? q1.y : hB1; hB2 = top ? q1.z : hB2;
        hC0 = bot ? q0.x : hC0; hC1 = bot ? q0.y : hC1; hC2 = bot ? q0.z : hC2;
        hD0 = bot ? q1.x : hD0; hD1 = bot ? q1.y : hD1; hD2 = bot ? q1.z : hD2;
    }

    // Gibbs weights (identical expressions to R6/R7 -> same rounding)
    const float e10 = expf(-1.0f / 0.1f);
    const float e2  = expf(-sqrtf(2.0f) / 0.1f);
    const float e20 = expf(-2.0f / 0.1f);
    const float e5  = expf(-sqrtf(5.0f) / 0.1f);

    float acc0, acc1, acc2, acc3, acc4, acc5, acc6, acc7, acc8;

    // ---- Sinkhorn iterations ----
#pragma unroll 1
    for (int it = 0; it < NITER; ++it) {
        CONV21(xu[0],xu[1],xu[2],xu[3],xu[4],xu[5],xu[6],xu[7],xu[8],
               1.0f, e10, e20, e10, e2, e5, e20, e5)
        UPDATE_PREP(xv, vb, WPv, RPv)

        CONV21(xv[0],xv[1],xv[2],xv[3],xv[4],xv[5],xv[6],xv[7],xv[8],
               1.0f, e10, e20, e10, e2, e5, e20, e5)
        UPDATE_PREP(xu, va, WPu, RPu)
    }

    // ---- loss: (u @ M) . v, M = K .* dist (center 0, corners dropped) ----
    const float s2f = sqrtf(2.0f), s5f = sqrtf(5.0f);
    CONV21(xu[0],xu[1],xu[2],xu[3],xu[4],xu[5],xu[6],xu[7],xu[8],
           0.0f, e10, e20 * 2.0f, e10, e2 * s2f, e5 * s5f, e20 * 2.0f, e5 * s5f)
    float lsum = acc0 * xv[0] + acc1 * xv[1] + acc2 * xv[2]
               + acc3 * xv[3] + acc4 * xv[4] + acc5 * xv[5]
               + acc6 * xv[6] + acc7 * xv[7] + acc8 * xv[8];

#pragma unroll
    for (int o = 1; o < 64; o <<= 1) lsum += __shfl_xor(lsum, o, 64);
    if (l == 0) atomicAdd(out, lsum);
}

extern "C" void kernel_launch(void* const* d_in, const int* in_sizes, int n_in,
                              void* d_out, int out_size, void* d_ws, size_t ws_size,
                              hipStream_t stream) {
    (void)in_sizes; (void)n_in; (void)out_size; (void)d_ws; (void)ws_size;
    const float* hm_gt = (const float*)d_in[0];
    const float* hm_pred = (const float*)d_in[1];
    const int* tops = (const int*)d_in[2];
    float* out = (float*)d_out;

    hipMemsetAsync(out, 0, sizeof(float), stream);
    sinkhorn_dpp<<<dim3(640), dim3(256), 0, stream>>>(hm_gt, hm_pred, tops, out);
}

// Round 9
// 225.718 us; speedup vs baseline: 1.1991x; 1.0182x over previous
//
#include <hip/hip_runtime.h>

#define TINYF 1e-8f
#define NITER 50
// LDS halo store: per field, 7 blocks of [4 rows][16 lanes][4 floats].
// Block b holds boundary rows written by wave b-1. Blocks 0/5 never written
// (stay zero -> crop edges); block 6 = trash for mid lanes.
#define HBLK 256
#define HFLD (7 * HBLK)

__device__ __forceinline__ float bperm(int addr4, float v) {
    return __int_as_float(__builtin_amdgcn_ds_bpermute(addr4, __float_as_int(v)));
}
// lane i <- lane i-1 within 16-lane DPP row; 0 at row edge (= crop left edge)
__device__ __forceinline__ float dpp_shr1(float v) {
    return __int_as_float(__builtin_amdgcn_update_dpp(0, __float_as_int(v), 0x111, 0xf, 0xf, true));
}
// lane i <- lane i+1 within 16-lane DPP row; 0 at row edge (= crop right edge)
__device__ __forceinline__ float dpp_shl1(float v) {
    return __int_as_float(__builtin_amdgcn_update_dpp(0, __float_as_int(v), 0x101, 0xf, 0xf, true));
}

// window-row prep: lane owns cols 3lc..3lc+2 of this row as C0_,C1_,C2_
#define ROWF(C0_, C1_, C2_) \
    L2 = dpp_shr1(C1_); L1 = dpp_shr1(C2_); R1 = dpp_shl1(C0_); R2 = dpp_shl1(C1_); \
    s1a = L1 + C1_; s1b = C0_ + C2_; s1c = C1_ + R1; \
    s2a = L2 + C2_; s2b = L1 + R1; s2c = C0_ + R2;
#define ROWL(C0_, C1_, C2_) \
    L1 = dpp_shr1(C2_); R1 = dpp_shl1(C0_); \
    s1a = L1 + C1_; s1b = C0_ + C2_; s1c = C1_ + R1;
#define ADX(A0_, A1_, A2_, C0_, C1_, C2_, KA, KB, KC) \
    A0_ += KA * C0_ + KB * s1a + KC * s2a; \
    A1_ += KA * C1_ + KB * s1b + KC * s2b; \
    A2_ += KA * C2_ + KB * s1c + KC * s2c;
#define AD2X(A0_, A1_, A2_, C0_, C1_, C2_, KA, KB) \
    A0_ += KA * C0_ + KB * s1a; \
    A1_ += KA * C1_ + KB * s1b; \
    A2_ += KA * C2_ + KB * s1c;

// issue ALL DS ops for this half-iteration up front (2 x b128 + 12 bperm)
#define HALO_ISSUE(G, RP) \
    q0 = *(const float4*)(RP); \
    q1 = *(const float4*)(RP + 64); \
    tA0 = bperm(upA, G[3]); tA1 = bperm(upA, G[4]); tA2 = bperm(upA, G[5]); \
    tB0 = bperm(upA, G[6]); tB1 = bperm(upA, G[7]); tB2 = bperm(upA, G[8]); \
    tC0 = bperm(dnA, G[0]); tC1 = bperm(dnA, G[1]); tC2 = bperm(dnA, G[2]); \
    tD0 = bperm(dnA, G[3]); tD1 = bperm(dnA, G[4]); tD2 = bperm(dnA, G[5]);

// own-row contributions only (wave-local registers, no DS dependence)
#define CONV_OWN(G, K00,K01,K02,K10,K11,K12,K20,K21) \
  { float L1,L2,R1,R2,s1a,s1b,s1c,s2a,s2b,s2c; \
    acc0=acc1=acc2=acc3=acc4=acc5=acc6=acc7=acc8=0.f; \
    ROWF(G[0], G[1], G[2]) \
    ADX (acc0,acc1,acc2, G[0],G[1],G[2], K00,K01,K02) \
    ADX (acc3,acc4,acc5, G[0],G[1],G[2], K10,K11,K12) \
    AD2X(acc6,acc7,acc8, G[0],G[1],G[2], K20,K21) \
    ROWF(G[3], G[4], G[5]) \
    ADX (acc0,acc1,acc2, G[3],G[4],G[5], K10,K11,K12) \
    ADX (acc3,acc4,acc5, G[3],G[4],G[5], K00,K01,K02) \
    ADX (acc6,acc7,acc8, G[3],G[4],G[5], K10,K11,K12) \
    ROWF(G[6], G[7], G[8]) \
    AD2X(acc0,acc1,acc2, G[6],G[7],G[8], K20,K21) \
    ADX (acc3,acc4,acc5, G[6],G[7],G[8], K10,K11,K12) \
    ADX (acc6,acc7,acc8, G[6],G[7],G[8], K00,K01,K02) \
  }

// resolve halos (first DS consume) + halo-row contributions
#define CONV_HALO(K10,K11,K12,K20,K21) \
  { float L1,L2,R1,R2,s1a,s1b,s1c,s2a,s2b,s2c; \
    const float hA0 = top ? q0.x : tA0, hA1 = top ? q0.y : tA1, hA2 = top ? q0.z : tA2; \
    const float hB0 = top ? q1.x : tB0, hB1 = top ? q1.y : tB1, hB2 = top ? q1.z : tB2; \
    const float hC0 = bot ? q0.x : tC0, hC1 = bot ? q0.y : tC1, hC2 = bot ? q0.z : tC2; \
    const float hD0 = bot ? q1.x : tD0, hD1 = bot ? q1.y : tD1, hD2 = bot ? q1.z : tD2; \
    ROWF(hB0, hB1, hB2) \
    ADX (acc0,acc1,acc2, hB0,hB1,hB2, K10,K11,K12) \
    AD2X(acc3,acc4,acc5, hB0,hB1,hB2, K20,K21) \
    ROWL(hA0, hA1, hA2) \
    AD2X(acc0,acc1,acc2, hA0,hA1,hA2, K20,K21) \
    ROWF(hC0, hC1, hC2) \
    AD2X(acc3,acc4,acc5, hC0,hC1,hC2, K20,K21) \
    ADX (acc6,acc7,acc8, hC0,hC1,hC2, K10,K11,K12) \
    ROWL(hD0, hD1, hD2) \
    AD2X(acc6,acc7,acc8, hD0,hD1,hD2, K20,K21) \
  }

// scale into field G and publish boundary rows (barrier follows at call site)
#define UPDATE_WRITE(G, M, WP) \
    G[0] = M[0] * __builtin_amdgcn_rcpf(acc0 + TINYF); \
    G[1] = M[1] * __builtin_amdgcn_rcpf(acc1 + TINYF); \
    G[2] = M[2] * __builtin_amdgcn_rcpf(acc2 + TINYF); \
    G[3] = M[3] * __builtin_amdgcn_rcpf(acc3 + TINYF); \
    G[4] = M[4] * __builtin_amdgcn_rcpf(acc4 + TINYF); \
    G[5] = M[5] * __builtin_amdgcn_rcpf(acc5 + TINYF); \
    G[6] = M[6] * __builtin_amdgcn_rcpf(acc6 + TINYF); \
    G[7] = M[7] * __builtin_amdgcn_rcpf(acc7 + TINYF); \
    G[8] = M[8] * __builtin_amdgcn_rcpf(acc8 + TINYF); \
    { float w0a = top ? G[0] : G[3], w0b = top ? G[1] : G[4], w0c = top ? G[2] : G[5]; \
      float w1a = top ? G[3] : G[6], w1b = top ? G[4] : G[7], w1c = top ? G[5] : G[8]; \
      *(float4*)(WP)      = make_float4(w0a, w0b, w0c, 0.f); \
      *(float4*)(WP + 64) = make_float4(w1a, w1b, w1c, 0.f); }

__global__ __launch_bounds__(256, 3)
void sinkhorn_sched(const float* __restrict__ hm_gt,
                    const float* __restrict__ hm_pred,
                    const int* __restrict__ tops,
                    float* __restrict__ out) {
    __shared__ __align__(16) float H[2 * HFLD];
    __shared__ float sred[8];

    const int t = threadIdx.x;
    const int w = t >> 6;                 // wave: strip rows 12w..12w+11
    const int l = t & 63;
    const int lr = l >> 4, lc = l & 15;   // 4 strip bands x 16 col-tiles (3 cols)
    const bool top = (lr == 0), bot = (lr == 3);

    const int blk = blockIdx.x;
    const int bi = blk / 40, rr = (blk / 5) % 8, cc = blk % 5;
    const int y0 = tops[(bi * 8 + rr) * 2 + 0];
    const int x0 = tops[(bi * 8 + rr) * 2 + 1];
    const float* srcA = hm_gt + (size_t)(bi * 5 + cc) * 25600;
    const float* srcB = hm_pred + (size_t)(bi * 5 + cc) * 25600;

    const int upA = ((l - 16) & 63) << 2;
    const int dnA = ((l + 16) & 63) << 2;

    float* Hu = H;
    float* Hv = H + HFLD;
    const int wblk = (top || bot) ? (w + 1) : 6;      // mid lanes -> trash block
    const int rblk = top ? w : (w + 2);               // w==0/top, w==3/bot hit zero blocks
    const int woff = wblk * HBLK + (top ? 0 : 2) * 64 + lc * 4;
    const int roff = rblk * HBLK + (top ? 2 : 0) * 64 + lc * 4;
    float* WPu = Hu + woff; const float* RPu = Hu + roff;
    float* WPv = Hv + woff; const float* RPv = Hv + roff;

    // ---- zero halo store ----
    const float4 z4 = make_float4(0.f, 0.f, 0.f, 0.f);
    for (int p = t; p < 2 * HFLD / 4; p += 256) ((float4*)H)[p] = z4;

    // ---- load 3x3 tiles; block-reduce sums ----
    const int gr = y0 + 12 * w + 3 * lr;
    const int gc = x0 + 3 * lc;
    float va[9], vb[9];
    float sA = 0.f, sB = 0.f;
#pragma unroll
    for (int i = 0; i < 3; ++i)
#pragma unroll
        for (int c = 0; c < 3; ++c) {
            const float A = srcA[(gr + i) * 160 + gc + c];
            const float B = srcB[(gr + i) * 160 + gc + c];
            va[3 * i + c] = A; vb[3 * i + c] = B;
            sA += A; sB += B;
        }
#pragma unroll
    for (int o = 1; o < 64; o <<= 1) {
        sA += __shfl_xor(sA, o, 64);
        sB += __shfl_xor(sB, o, 64);
    }
    if (l == 0) { sred[w] = sA; sred[4 + w] = sB; }
    __syncthreads();   // also covers H zeroing
    sA = sred[0] + sred[1] + sred[2] + sred[3];
    sB = sred[4] + sred[5] + sred[6] + sred[7];
    const float nA = 1.0f / (sA + TINYF);
    const float nB = 1.0f / (sB + TINYF);
#pragma unroll
    for (int k = 0; k < 9; ++k) { va[k] *= nA; vb[k] *= nB; }

    // ---- u0 = 1/n; publish boundary ----
    float xu[9], xv[9];
    const float u0 = 1.0f / 2304.0f;
#pragma unroll
    for (int k = 0; k < 9; ++k) xu[k] = u0;
    *(float4*)(WPu)      = make_float4(u0, u0, u0, 0.f);
    *(float4*)(WPu + 64) = make_float4(u0, u0, u0, 0.f);
    __syncthreads();

    // Gibbs weights (identical expressions to R6-R8 -> same rounding)
    const float e10 = expf(-1.0f / 0.1f);
    const float e2  = expf(-sqrtf(2.0f) / 0.1f);
    const float e20 = expf(-2.0f / 0.1f);
    const float e5  = expf(-sqrtf(5.0f) / 0.1f);

    float acc0, acc1, acc2, acc3, acc4, acc5, acc6, acc7, acc8;
    float4 q0, q1;
    float tA0, tA1, tA2, tB0, tB1, tB2, tC0, tC1, tC2, tD0, tD1, tD2;

    // ---- Sinkhorn iterations ----
#pragma unroll 1
    for (int it = 0; it < NITER; ++it) {
        // u @ K -> v
        HALO_ISSUE(xu, RPu)
        CONV_OWN(xu, 1.0f, e10, e20, e10, e2, e5, e20, e5)
        CONV_HALO(e10, e2, e5, e20, e5)
        UPDATE_WRITE(xv, vb, WPv)
        __syncthreads();

        // v @ K -> u
        HALO_ISSUE(xv, RPv)
        CONV_OWN(xv, 1.0f, e10, e20, e10, e2, e5, e20, e5)
        CONV_HALO(e10, e2, e5, e20, e5)
        UPDATE_WRITE(xu, va, WPu)
        __syncthreads();
    }

    // ---- loss: (u @ M) . v, M = K .* dist (center 0, corners dropped) ----
    const float s2f = sqrtf(2.0f), s5f = sqrtf(5.0f);
    const float m01 = e10, m02 = e20 * 2.0f, m11 = e2 * s2f, m12 = e5 * s5f;
    HALO_ISSUE(xu, RPu)
    CONV_OWN(xu, 0.0f, m01, m02, m01, m11, m12, m02, m12)
    CONV_HALO(m01, m11, m12, m02, m12)
    float lsum = acc0 * xv[0] + acc1 * xv[1] + acc2 * xv[2]
               + acc3 * xv[3] + acc4 * xv[4] + acc5 * xv[5]
               + acc6 * xv[6] + acc7 * xv[7] + acc8 * xv[8];

#pragma unroll
    for (int o = 1; o < 64; o <<= 1) lsum += __shfl_xor(lsum, o, 64);
    if (l == 0) atomicAdd(out, lsum);
}

extern "C" void kernel_launch(void* const* d_in, const int* in_sizes, int n_in,
                              void* d_out, int out_size, void* d_ws, size_t ws_size,
                              hipStream_t stream) {
    (void)in_sizes; (void)n_in; (void)out_size; (void)d_ws; (void)ws_size;
    const float* hm_gt = (const float*)d_in[0];
    const float* hm_pred = (const float*)d_in[1];
    const int* tops = (const int*)d_in[2];
    float* out = (float*)d_out;

    hipMemsetAsync(out, 0, sizeof(float), stream);
    sinkhorn_sched<<<dim3(640), dim3(256), 0, stream>>>(hm_gt, hm_pred, tops, out);
}